// Round 4
// baseline (4842.809 us; speedup 1.0000x reference)
//
#include <hip/hip_runtime.h>
#include <stdint.h>

typedef _Float16 half_t;
typedef _Float16 half8v __attribute__((ext_vector_type(8)));
typedef float    f32x4  __attribute__((ext_vector_type(4)));

#define Hd 512
#define Td 400
#define Sd 400
#define Bd 32

// ws layout (bytes)
#define OFF_BAR   0ull          // 8 groups x 32 u32 slots = 1024
#define OFF_HBUF  1024ull       // f16 [32][512] = 32768
#define OFF_PH    33792ull      // f32 [8][4][512] = 65536
#define OFF_CTX   99328ull      // f32 [8][2][4][512] = 131072 (atomic-accumulated ctx, dbl-buffered)
#define OFF_LB    230400ull     // f32 [8][2][4] = 256 (softmax denominators)
#define ZERO_WORDS 57664        // bytes [0,230656) zeroed by k_init
#define OFF_ENC   1048576ull    // f16 [400][32][512]
#define OFF_PENC  14155776ull   // f16 [400][32][512]
#define OFF_XS    27262976ull   // f16 [400][32][512]
#define OFF_GIX   40370176ull   // f16 [400][32][1536]
#define OFF_H2A   79691776ull   // f16 [400][32][512]
#define OFF_W1    92798976ull   // f16 [2048][512]  (fc_W rows 0-511, Whh rows 512-2047)
#define OFF_W3    94896128ull   // f16 [1536][512]  (Wih_c)
#define OFF_WX    96468992ull   // f16 [1536][512]  (Wih_x)
#define OFF_SPEC  98041856ull   // f16 [512][512]

static __device__ __forceinline__ float fast_tanh(float x){
  float t = __builtin_amdgcn_exp2f(x * 2.8853900817779268f);   // exp(2x)
  return fmaf(-2.f, __builtin_amdgcn_rcpf(t + 1.f), 1.f);
}
static __device__ __forceinline__ float fast_sigmoid(float x){
  float t = __builtin_amdgcn_exp2f(x * -1.4426950408889634f);  // exp(-x)
  return __builtin_amdgcn_rcpf(1.f + t);
}

// L1-bypassing relaxed loads (L2-served, no cache-maintenance codegen)
static __device__ __forceinline__ float ld_f32_l2(const float* p){
  return __hip_atomic_load(p, __ATOMIC_RELAXED, __HIP_MEMORY_SCOPE_AGENT);
}
static __device__ __forceinline__ unsigned long long ld_u64_l2(const void* p){
  return __hip_atomic_load((const unsigned long long*)p, __ATOMIC_RELAXED,
                           __HIP_MEMORY_SCOPE_AGENT);
}

// ---------------- init: zero barrier/hbuf/ctx/lb region ------------------
__global__ void k_init(char* ws){
  unsigned* p = (unsigned*)ws;
  int i = blockIdx.x*blockDim.x + threadIdx.x;
  if (i < ZERO_WORDS) p[i] = 0u;
}

// ---------------- prep: f32 -> f16 staging -------------------------------
__global__ void k_prep_enc(const float* __restrict__ src, half_t* __restrict__ dst, int n){
  int st = gridDim.x*blockDim.x;
  for (int i = blockIdx.x*blockDim.x + threadIdx.x; i < n; i += st)
    dst[i] = (half_t)src[i];
}
__global__ void k_prep_xs(const float* __restrict__ dec, half_t* __restrict__ dst){
  const int n = Td*Bd*Hd; int st = gridDim.x*blockDim.x;
  for (int i = blockIdx.x*blockDim.x + threadIdx.x; i < n; i += st){
    float v = (i < Bd*Hd) ? 0.f : dec[i - Bd*Hd];   // teacher forcing shift
    dst[i] = (half_t)v;
  }
}
__global__ void k_prep_w(const float* __restrict__ fcW, const float* __restrict__ Wih,
                         const float* __restrict__ Whh, const float* __restrict__ specW,
                         char* __restrict__ ws){
  half_t* w1 = (half_t*)(ws + OFF_W1);
  half_t* w3 = (half_t*)(ws + OFF_W3);
  half_t* wx = (half_t*)(ws + OFF_WX);
  half_t* sp = (half_t*)(ws + OFF_SPEC);
  int st = gridDim.x*blockDim.x;
  int t0 = blockIdx.x*blockDim.x + threadIdx.x;
  for (int i = t0; i < 2048*512; i += st)
    w1[i] = (half_t)((i < 512*512) ? fcW[i] : Whh[i - 512*512]);
  for (int i = t0; i < 1536*512; i += st){
    int r = i >> 9, k = i & 511;
    wx[i] = (half_t)Wih[r*1024 + k];
    w3[i] = (half_t)Wih[r*1024 + 512 + k];
  }
  for (int i = t0; i < 512*512; i += st) sp[i] = (half_t)specW[i];
}

// ---------------- bulk MFMA GEMM: C[M,N] = A[M,512] @ W[N,512]^T ---------
template<int MODE>
__global__ __launch_bounds__(256) void k_gemm(const half_t* __restrict__ A,
                                              const half_t* __restrict__ W,
                                              void* __restrict__ out, int N,
                                              const float* __restrict__ bias)
{
  __shared__ __align__(16) half_t As[64*32];
  __shared__ __align__(16) half_t Ws[64*32];
  const int tid = threadIdx.x;
  const int m0 = blockIdx.y * 64, n0 = blockIdx.x * 64;
  const int trow = tid >> 2, tseg = tid & 3;
  const int wv = tid >> 6, ln = tid & 63;
  const int fr = ln & 15, ko = (ln >> 4) * 8;
  f32x4 acc[4];
  #pragma unroll
  for (int cb = 0; cb < 4; ++cb){ acc[cb][0]=0.f; acc[cb][1]=0.f; acc[cb][2]=0.f; acc[cb][3]=0.f; }
  for (int kk = 0; kk < 512; kk += 32){
    ((uint4*)As)[tid] = *(const uint4*)(A + (size_t)(m0 + trow)*512 + kk + tseg*8);
    ((uint4*)Ws)[tid] = *(const uint4*)(W + (size_t)(n0 + trow)*512 + kk + tseg*8);
    __syncthreads();
    half8v af = *(const half8v*)&As[(wv*16 + fr)*32 + ko];
    #pragma unroll
    for (int cb = 0; cb < 4; ++cb){
      half8v bf = *(const half8v*)&Ws[(cb*16 + fr)*32 + ko];
      acc[cb] = __builtin_amdgcn_mfma_f32_16x16x32_f16(af, bf, acc[cb], 0, 0, 0);
    }
    __syncthreads();
  }
  #pragma unroll
  for (int cb = 0; cb < 4; ++cb){
    #pragma unroll
    for (int i = 0; i < 4; ++i){
      int gr = m0 + wv*16 + (ln >> 4)*4 + i;
      int gc = n0 + cb*16 + (ln & 15);
      if (MODE == 0){
        ((half_t*)out)[(size_t)gr*N + gc] = (half_t)acc[cb][i];
      } else {
        int tt = gr >> 5, bb = gr & 31;
        ((float*)out)[(size_t)bb*(Td*Hd) + (size_t)tt*Hd + gc] = acc[cb][i] + bias[gc];
      }
    }
  }
}

// ---------------- gate projection ---------------------------------------
__global__ __launch_bounds__(256) void k_gate(const half_t* __restrict__ h2a,
    const float* __restrict__ gW, const float* __restrict__ gb, float* __restrict__ out)
{
  const int o = blockIdx.x * 4 + (threadIdx.x >> 6);
  const int lane = threadIdx.x & 63;
  const half8v hv = *(const half8v*)(h2a + (size_t)o*512 + lane*8);
  float a = 0.f;
  #pragma unroll
  for (int i = 0; i < 8; ++i) a = fmaf((float)hv[i], gW[lane*8 + i], a);
  #pragma unroll
  for (int o2 = 1; o2 < 64; o2 <<= 1) a += __shfl_xor(a, o2);
  if (lane == 0){
    const int tt = o >> 5, bb = o & 31;
    out[Bd*Td*Hd + bb*Td + tt] = a + gb[0];
  }
}

// ---------------- group barrier: distributed slots, no RMW ---------------
static __device__ __forceinline__ void gbar(unsigned* slots, int m, unsigned bt){
  __syncthreads();                              // drains vmcnt: data L2-visible
  if (threadIdx.x < 64){
    if (threadIdx.x == 0)
      __hip_atomic_store(&slots[m], bt, __ATOMIC_RELAXED, __HIP_MEMORY_SCOPE_AGENT);
    const unsigned* sp = &slots[threadIdx.x & 31];
    for (;;){
      unsigned v = __hip_atomic_load(sp, __ATOMIC_RELAXED, __HIP_MEMORY_SCOPE_AGENT);
      if (__all((int)(v >= bt))) break;
      __builtin_amdgcn_s_sleep(1);
    }
  }
  __syncthreads();
}

// ---------------- persistent recurrent kernel ----------------------------
// 256 blocks x 512 thr. group g = blockIdx%8 (XCD), member m = blockIdx/8.
// Group owns batches b0..b0+3. MFMA phases; 3 group barriers/step.
__global__ __launch_bounds__(512, 2) void k_main(char* __restrict__ ws,
                                                 const float* __restrict__ attw)
{
  const int g = blockIdx.x & 7;
  const int m = blockIdx.x >> 3;
  const int tid = threadIdx.x;
  const int lane = tid & 63;
  const int w = tid >> 6;
  const int b0 = g * 4;
  const int r16 = lane & 15, kg = lane >> 4;

  half_t* hbuf = (half_t*)(ws + OFF_HBUF);
  float*  ph_g = (float*)(ws + OFF_PH)  + g*2048;
  float*  ctxp = (float*)(ws + OFF_CTX) + g*4096;
  float*  lbp  = (float*)(ws + OFF_LB)  + g*8;
  unsigned* slots = (unsigned*)(ws + OFF_BAR) + g*32;
  const half_t* Penc = (const half_t*)(ws + OFF_PENC);
  const half_t* ench = (const half_t*)(ws + OFF_ENC);
  const half_t* gix  = (const half_t*)(ws + OFF_GIX);
  half_t* h2a = (half_t*)(ws + OFF_H2A);
  const half_t* w1 = (const half_t*)(ws + OFF_W1);
  const half_t* w3 = (const half_t*)(ws + OFF_W3);

  __shared__ __align__(16) half_t hs[2048];     // h staging [4][512]
  __shared__ __align__(16) half_t ctxs[2048];   // ctx staging [4][512] (normalized)
  __shared__ __align__(16) float accb[8][4][16];   // ph split-K partials
  __shared__ __align__(16) float ghb[3][2][4][16]; // gh partials [gate][kh][b][j]
  __shared__ __align__(16) float gib[3][2][4][16]; // gi_c partials
  __shared__ float es[64];

  // --- register-resident MFMA A-fragments (weights) ----------------------
  // P1: fc_W rows m*16+r16, ksteps {2w, 2w+1}
  half8v w1a[2];
  {
    const half_t* wr = w1 + (size_t)(m*16 + r16)*512;
    #pragma unroll
    for (int q = 0; q < 2; ++q)
      w1a[q] = *(const half8v*)(wr + (2*w+q)*32 + kg*8);
  }
  // gh/gi: waves 0..5 -> (gate=w>>1, kh=w&1), 8 ksteps each
  half8v wha[8], w3a[8];
  if (w < 6){
    const int gate = w >> 1, kh = w & 1;
    const half_t* wr1 = w1 + (size_t)(512 + gate*512 + m*16 + r16)*512;
    const half_t* wr3 = w3 + (size_t)(gate*512 + m*16 + r16)*512;
    #pragma unroll
    for (int i = 0; i < 8; ++i){
      wha[i] = *(const half8v*)(wr1 + (kh*8+i)*32 + kg*8);
      w3a[i] = *(const half8v*)(wr3 + (kh*8+i)*32 + kg*8);
    }
  }
  float awr[8];
  #pragma unroll
  for (int i = 0; i < 8; ++i) awr[i] = attw[lane*8 + i];

  const int b_l = m & 3, ch = m >> 2;           // phase2 role
  const int bglob = b0 + b_l;
  const int s0 = (w < 6) ? 6*w : 36 + 7*(w-6);  // 50 = 6*6 + 2*7 (waves 6,7 skip gh)
  const int ns = (w < 6) ? 6 : 7;
  float h2keep = 0.f;                           // own h element, tid<64
  unsigned bt = 0;

  for (int t = 0; t < Td; ++t){
    const int cur = t & 1, nxt = cur ^ 1;
    // ---------- phase 1: ph rows m*16..+16 via MFMA (split-K over 8 waves)
    ((unsigned long long*)hs)[tid] =
        ld_u64_l2(((const unsigned long long*)(hbuf + b0*512)) + tid);
    __syncthreads();
    {
      f32x4 acc = {0.f, 0.f, 0.f, 0.f};
      #pragma unroll
      for (int q = 0; q < 2; ++q){
        half8v bf = *(const half8v*)(hs + (lane&3)*512 + (2*w+q)*32 + kg*8);
        acc = __builtin_amdgcn_mfma_f32_16x16x32_f16(w1a[q], bf, acc, 0, 0, 0);
      }
      if (r16 < 4) *((f32x4*)&accb[w][lane&3][kg*4]) = acc;
    }
    __syncthreads();
    if (tid < 64){
      const int c = tid >> 4, r = tid & 15;
      float s = 0.f;
      #pragma unroll
      for (int w2 = 0; w2 < 8; ++w2) s += accb[w2][c][r];
      ph_g[c*512 + m*16 + r] = s;
    }
    gbar(slots, m, ++bt);
    // ---------- phase 2: gh MFMA (overlap) + attention + ctx atomic partials
    {
      union { unsigned long long u[4]; float f[8]; } phu;
      const float* php = ph_g + b_l*512 + lane*8;
      #pragma unroll
      for (int q2 = 0; q2 < 4; ++q2)
        phu.u[q2] = ld_u64_l2(((const unsigned long long*)php) + q2);
      const half_t* pbase = Penc + ((size_t)(ch*50 + s0)*32 + bglob)*512 + lane*8;
      half8v pv[7];
      #pragma unroll
      for (int k = 0; k < 7; ++k){
        int kk = (k < ns) ? k : (ns-1);
        pv[k] = *(const half8v*)(pbase + (size_t)kk*16384);
      }
      if (w < 6){                              // gh: needed only in phase 3
        const int gate = w >> 1, kh = w & 1;
        f32x4 ga = {0.f, 0.f, 0.f, 0.f};
        #pragma unroll
        for (int i = 0; i < 8; ++i){
          half8v bf = *(const half8v*)(hs + (lane&3)*512 + (kh*8+i)*32 + kg*8);
          ga = __builtin_amdgcn_mfma_f32_16x16x32_f16(wha[i], bf, ga, 0, 0, 0);
        }
        if (r16 < 4) *((f32x4*)&ghb[gate][kh][lane&3][kg*4]) = ga;
      }
      #pragma unroll
      for (int k = 0; k < 7; ++k){
        if (k >= ns) break;
        float a = 0.f;
        #pragma unroll
        for (int i = 0; i < 8; ++i)
          a = fmaf(fast_tanh((float)pv[k][i] + phu.f[i]), awr[i], a);
        #pragma unroll
        for (int o = 1; o < 64; o <<= 1) a += __shfl_xor(a, o);
        if (lane == 0) es[s0 + k] = a;
      }
      __syncthreads();
      if (tid < 64){
        float ev = 0.f;
        if (tid < 50){
          ev = __builtin_amdgcn_exp2f((es[tid] - 20.f) * 1.4426950408889634f);
          es[tid] = ev;     // fixed-offset softmax (|e| <= ||att_w||_1 ~ 18)
        }
        #pragma unroll
        for (int o = 1; o < 64; o <<= 1) ev += __shfl_xor(ev, o);
        if (tid == 0) unsafeAtomicAdd(&lbp[cur*4 + b_l], ev);
      }
      __syncthreads();
      float acc2 = 0.f;
      const half_t* ep = ench + ((size_t)(ch*50)*32 + bglob)*512 + tid;
      #pragma unroll 10
      for (int s = 0; s < 50; ++s)
        acc2 = fmaf((float)ep[(size_t)s*16384], es[s], acc2);
      unsafeAtomicAdd(&ctxp[cur*2048 + b_l*512 + tid], acc2);
    }
    gbar(slots, m, ++bt);
    // ---------- phase 3: normalize ctx BEFORE f16 pack (raw ctx ~1e-6 is
    // f16-subnormal — R3's bug), gi_c MFMA on normalized ctx, GRU update ---
    {
      const float Lrcp =
          __builtin_amdgcn_rcpf(ld_f32_l2(&lbp[cur*4 + (tid >> 7)]));
      union { unsigned long long u[2]; float f[4]; } cu;
      const unsigned long long* cp = (const unsigned long long*)(ctxp + cur*2048 + tid*4);
      cu.u[0] = ld_u64_l2(cp);
      cu.u[1] = ld_u64_l2(cp + 1);
      union { half_t h[4]; unsigned long long u; } cpk;
      #pragma unroll
      for (int i = 0; i < 4; ++i) cpk.h[i] = (half_t)(cu.f[i] * Lrcp);
      ((unsigned long long*)ctxs)[tid] = cpk.u;
      __syncthreads();
      if (w < 6){
        const int gate = w >> 1, kh = w & 1;
        f32x4 ia = {0.f, 0.f, 0.f, 0.f};
        #pragma unroll
        for (int i = 0; i < 8; ++i){
          half8v bf = *(const half8v*)(ctxs + (lane&3)*512 + (kh*8+i)*32 + kg*8);
          ia = __builtin_amdgcn_mfma_f32_16x16x32_f16(w3a[i], bf, ia, 0, 0, 0);
        }
        if (r16 < 4) *((f32x4*)&gib[gate][kh][lane&3][kg*4]) = ia;
      }
      __syncthreads();
      if (tid < 64){
        const int bl = tid >> 4, jl = tid & 15;
        const int j = m*16 + jl, bg = b0 + bl;
        const half_t* gp = gix + ((size_t)t*32 + bg)*1536;
        float xr = (float)gp[j]        + gib[0][0][bl][jl] + gib[0][1][bl][jl]
                                       + ghb[0][0][bl][jl] + ghb[0][1][bl][jl];
        float xz = (float)gp[512 + j]  + gib[1][0][bl][jl] + gib[1][1][bl][jl]
                                       + ghb[1][0][bl][jl] + ghb[1][1][bl][jl];
        float xn = (float)gp[1024 + j] + gib[2][0][bl][jl] + gib[2][1][bl][jl];
        float gnh = ghb[2][0][bl][jl] + ghb[2][1][bl][jl];
        float r = fast_sigmoid(xr);
        float z = fast_sigmoid(xz);
        float n = fast_tanh(xn + r * gnh);
        float h2v = (1.f - z) * n + z * h2keep;
        h2keep = h2v;
        hbuf[bg*512 + j] = (half_t)h2v;
        h2a[((size_t)t*32 + bg)*512 + j] = (half_t)h2v;
      }
      // zero next-step accumulators (consumed; writers come after bar3)
      ((unsigned long long*)(ctxp + nxt*2048))[tid] = 0ull;
      ((unsigned long long*)(ctxp + nxt*2048))[tid + 512] = 0ull;
      if (tid < 4) lbp[nxt*4 + tid] = 0.f;
    }
    gbar(slots, m, ++bt);
  }
}

// ---------------- launch --------------------------------------------------
extern "C" void kernel_launch(void* const* d_in, const int* in_sizes, int n_in,
                              void* d_out, int out_size, void* d_ws, size_t ws_size,
                              hipStream_t stream)
{
  const float* dec   = (const float*)d_in[0];
  const float* enc   = (const float*)d_in[1];
  const float* fcW   = (const float*)d_in[2];
  const float* attw  = (const float*)d_in[3];
  const float* Wih   = (const float*)d_in[4];
  const float* Whh   = (const float*)d_in[5];
  const float* specW = (const float*)d_in[6];
  const float* specb = (const float*)d_in[7];
  const float* gateW = (const float*)d_in[8];
  const float* gateb = (const float*)d_in[9];
  char* ws = (char*)d_ws;
  float* out = (float*)d_out;

  hipLaunchKernelGGL(k_init, dim3(226), dim3(256), 0, stream, ws);
  hipLaunchKernelGGL(k_prep_enc, dim3(2048), dim3(256), 0, stream,
                     enc, (half_t*)(ws + OFF_ENC), Sd*Bd*Hd);
  hipLaunchKernelGGL(k_prep_xs, dim3(2048), dim3(256), 0, stream,
                     dec, (half_t*)(ws + OFF_XS));
  hipLaunchKernelGGL(k_prep_w, dim3(1024), dim3(256), 0, stream,
                     fcW, Wih, Whh, specW, ws);
  // Penc = enc @ fc_W^T   (M=12800, N=512)
  hipLaunchKernelGGL((k_gemm<0>), dim3(8, 200), dim3(256), 0, stream,
                     (const half_t*)(ws + OFF_ENC), (const half_t*)(ws + OFF_W1),
                     (void*)(ws + OFF_PENC), 512, (const float*)nullptr);
  // GI_x = xs @ Wih_x^T   (M=12800, N=1536)
  hipLaunchKernelGGL((k_gemm<0>), dim3(24, 200), dim3(256), 0, stream,
                     (const half_t*)(ws + OFF_XS), (const half_t*)(ws + OFF_WX),
                     (void*)(ws + OFF_GIX), 1536, (const float*)nullptr);
  // recurrent loop
  hipLaunchKernelGGL(k_main, dim3(256), dim3(512), 0, stream, ws, attw);
  // mels = h2 @ spec_W^T + b, written (B,T,H)
  hipLaunchKernelGGL((k_gemm<1>), dim3(8, 200), dim3(256), 0, stream,
                     (const half_t*)(ws + OFF_H2A), (const half_t*)(ws + OFF_SPEC),
                     (void*)out, 512, specb);
  // gates = h2 @ gate_W + b, written (B,T)
  hipLaunchKernelGGL(k_gate, dim3(3200), dim3(256), 0, stream,
                     (const half_t*)(ws + OFF_H2A), gateW, gateb, out);
}

// Round 5
// 3589.651 us; speedup vs baseline: 1.3491x; 1.3491x over previous
//
#include <hip/hip_runtime.h>
#include <stdint.h>

typedef _Float16 half_t;
typedef _Float16 half2v __attribute__((ext_vector_type(2)));
typedef _Float16 half8v __attribute__((ext_vector_type(8)));
typedef float    f32x4  __attribute__((ext_vector_type(4)));
typedef float    f32x2  __attribute__((ext_vector_type(2)));

#define Hd 512
#define Td 400
#define Sd 400
#define Bd 32
#define HS_STR 520   // padded LDS stride (halfs) for hs/ctxs: breaks 4-way bank conflicts

// ws layout (bytes)
#define OFF_BAR   0ull          // 8 groups x 32 u32 slots = 1024
#define OFF_HBUF  1024ull       // f16 [32][512] = 32768
#define OFF_PH    33792ull      // f32 [8][4][512] = 65536
#define OFF_CTXP  99328ull      // f32 [8][4][8][512] = 524288 (plain per-chunk partials)
#define OFF_LB    623616ull     // f32 [8][4][8] = 1024
#define ZERO_WORDS 8448         // bytes [0,33792): barrier slots + hbuf
#define OFF_ENC   1048576ull    // f16 [400][32][512]
#define OFF_PENC  14155776ull   // f16 [400][32][512]
#define OFF_XS    27262976ull   // f16 [400][32][512]
#define OFF_GIX   40370176ull   // f16 [400][32][1536]
#define OFF_H2A   79691776ull   // f16 [400][32][512]
#define OFF_W1    92798976ull   // f16 [2048][512]  (fc_W rows 0-511, Whh rows 512-2047)
#define OFF_W3    94896128ull   // f16 [1536][512]  (Wih_c)
#define OFF_WX    96468992ull   // f16 [1536][512]  (Wih_x)
#define OFF_SPEC  98041856ull   // f16 [512][512]

static __device__ __forceinline__ float fast_tanh(float x){
  float t = __builtin_amdgcn_exp2f(x * 2.8853900817779268f);
  return fmaf(-2.f, __builtin_amdgcn_rcpf(t + 1.f), 1.f);
}
static __device__ __forceinline__ float fast_sigmoid(float x){
  float t = __builtin_amdgcn_exp2f(x * -1.4426950408889634f);
  return __builtin_amdgcn_rcpf(1.f + t);
}
// Pade tanh: clamp(+-3) then x(27+x^2)/(27+9x^2); |err|<=5e-3, 1 trans op.
static __device__ __forceinline__ float pade_tanh(float x){
  x = fminf(3.f, fmaxf(-3.f, x));
  float t2 = x * x;
  return (x * (27.f + t2)) * __builtin_amdgcn_rcpf(fmaf(t2, 9.f, 27.f));
}

// L1-bypassing relaxed loads (L2-served, no cache-maintenance codegen)
static __device__ __forceinline__ float ld_f32_l2(const float* p){
  return __hip_atomic_load(p, __ATOMIC_RELAXED, __HIP_MEMORY_SCOPE_AGENT);
}
static __device__ __forceinline__ unsigned long long ld_u64_l2(const void* p){
  return __hip_atomic_load((const unsigned long long*)p, __ATOMIC_RELAXED,
                           __HIP_MEMORY_SCOPE_AGENT);
}

// ---------------- init: zero barrier slots + hbuf ------------------------
__global__ void k_init(char* ws){
  unsigned* p = (unsigned*)ws;
  int i = blockIdx.x*blockDim.x + threadIdx.x;
  if (i < ZERO_WORDS) p[i] = 0u;
}

// ---------------- prep: f32 -> f16 staging -------------------------------
__global__ void k_prep_enc(const float* __restrict__ src, half_t* __restrict__ dst, int n){
  int st = gridDim.x*blockDim.x;
  for (int i = blockIdx.x*blockDim.x + threadIdx.x; i < n; i += st)
    dst[i] = (half_t)src[i];
}
__global__ void k_prep_xs(const float* __restrict__ dec, half_t* __restrict__ dst){
  const int n = Td*Bd*Hd; int st = gridDim.x*blockDim.x;
  for (int i = blockIdx.x*blockDim.x + threadIdx.x; i < n; i += st){
    float v = (i < Bd*Hd) ? 0.f : dec[i - Bd*Hd];   // teacher forcing shift
    dst[i] = (half_t)v;
  }
}
__global__ void k_prep_w(const float* __restrict__ fcW, const float* __restrict__ Wih,
                         const float* __restrict__ Whh, const float* __restrict__ specW,
                         char* __restrict__ ws){
  half_t* w1 = (half_t*)(ws + OFF_W1);
  half_t* w3 = (half_t*)(ws + OFF_W3);
  half_t* wx = (half_t*)(ws + OFF_WX);
  half_t* sp = (half_t*)(ws + OFF_SPEC);
  int st = gridDim.x*blockDim.x;
  int t0 = blockIdx.x*blockDim.x + threadIdx.x;
  for (int i = t0; i < 2048*512; i += st)
    w1[i] = (half_t)((i < 512*512) ? fcW[i] : Whh[i - 512*512]);
  for (int i = t0; i < 1536*512; i += st){
    int r = i >> 9, k = i & 511;
    wx[i] = (half_t)Wih[r*1024 + k];
    w3[i] = (half_t)Wih[r*1024 + 512 + k];
  }
  for (int i = t0; i < 512*512; i += st) sp[i] = (half_t)specW[i];
}

// ---------------- bulk MFMA GEMM: C[M,N] = A[M,512] @ W[N,512]^T ---------
template<int MODE>
__global__ __launch_bounds__(256) void k_gemm(const half_t* __restrict__ A,
                                              const half_t* __restrict__ W,
                                              void* __restrict__ out, int N,
                                              const float* __restrict__ bias)
{
  __shared__ __align__(16) half_t As[64*32];
  __shared__ __align__(16) half_t Ws[64*32];
  const int tid = threadIdx.x;
  const int m0 = blockIdx.y * 64, n0 = blockIdx.x * 64;
  const int trow = tid >> 2, tseg = tid & 3;
  const int wv = tid >> 6, ln = tid & 63;
  const int fr = ln & 15, ko = (ln >> 4) * 8;
  f32x4 acc[4];
  #pragma unroll
  for (int cb = 0; cb < 4; ++cb){ acc[cb][0]=0.f; acc[cb][1]=0.f; acc[cb][2]=0.f; acc[cb][3]=0.f; }
  for (int kk = 0; kk < 512; kk += 32){
    ((uint4*)As)[tid] = *(const uint4*)(A + (size_t)(m0 + trow)*512 + kk + tseg*8);
    ((uint4*)Ws)[tid] = *(const uint4*)(W + (size_t)(n0 + trow)*512 + kk + tseg*8);
    __syncthreads();
    half8v af = *(const half8v*)&As[(wv*16 + fr)*32 + ko];
    #pragma unroll
    for (int cb = 0; cb < 4; ++cb){
      half8v bf = *(const half8v*)&Ws[(cb*16 + fr)*32 + ko];
      acc[cb] = __builtin_amdgcn_mfma_f32_16x16x32_f16(af, bf, acc[cb], 0, 0, 0);
    }
    __syncthreads();
  }
  #pragma unroll
  for (int cb = 0; cb < 4; ++cb){
    #pragma unroll
    for (int i = 0; i < 4; ++i){
      int gr = m0 + wv*16 + (ln >> 4)*4 + i;
      int gc = n0 + cb*16 + (ln & 15);
      if (MODE == 0){
        ((half_t*)out)[(size_t)gr*N + gc] = (half_t)acc[cb][i];
      } else {
        int tt = gr >> 5, bb = gr & 31;
        ((float*)out)[(size_t)bb*(Td*Hd) + (size_t)tt*Hd + gc] = acc[cb][i] + bias[gc];
      }
    }
  }
}

// ---------------- gate projection ---------------------------------------
__global__ __launch_bounds__(256) void k_gate(const half_t* __restrict__ h2a,
    const float* __restrict__ gW, const float* __restrict__ gb, float* __restrict__ out)
{
  const int o = blockIdx.x * 4 + (threadIdx.x >> 6);
  const int lane = threadIdx.x & 63;
  const half8v hv = *(const half8v*)(h2a + (size_t)o*512 + lane*8);
  float a = 0.f;
  #pragma unroll
  for (int i = 0; i < 8; ++i) a = fmaf((float)hv[i], gW[lane*8 + i], a);
  #pragma unroll
  for (int o2 = 1; o2 < 64; o2 <<= 1) a += __shfl_xor(a, o2);
  if (lane == 0){
    const int tt = o >> 5, bb = o & 31;
    out[Bd*Td*Hd + bb*Td + tt] = a + gb[0];
  }
}

// ---------------- barrier primitives (distributed slots, no RMW) ---------
static __device__ __forceinline__ void slot_store(unsigned* slots, int m, unsigned v){
  __hip_atomic_store(&slots[m], v, __ATOMIC_RELAXED, __HIP_MEMORY_SCOPE_AGENT);
}
static __device__ __forceinline__ void wait_slots(unsigned* slots, unsigned v){
  if (threadIdx.x < 64){
    const unsigned* sp = &slots[threadIdx.x & 31];
    for (;;){
      unsigned x = __hip_atomic_load(sp, __ATOMIC_RELAXED, __HIP_MEMORY_SCOPE_AGENT);
      if (__all((int)(x >= v))) break;
      __builtin_amdgcn_s_sleep(1);
    }
  }
  __syncthreads();
}

// ---------------- persistent recurrent kernel ----------------------------
// 256 blocks x 512 thr, 1 block/CU (LDS ~119 KB). group g = blockIdx%8 (XCD),
// member m = blockIdx/8. Group owns batches b0..b0+3; block role (b_l, ch).
// Penc/enc tiles LDS-resident for the whole loop. 3 barriers/step with
// arrive/wait split: gh-MFMA hides bar1, gix prefetch hides bar2.
__global__ __launch_bounds__(512, 2) void k_main(char* __restrict__ ws,
                                                 const float* __restrict__ attw)
{
  const int g = blockIdx.x & 7;
  const int m = blockIdx.x >> 3;
  const int tid = threadIdx.x;
  const int lane = tid & 63;
  const int w = tid >> 6;
  const int b0 = g * 4;
  const int r16 = lane & 15, kg = lane >> 4;

  half_t* hbuf = (half_t*)(ws + OFF_HBUF);
  float*  ph_g = (float*)(ws + OFF_PH)   + g*2048;
  float*  ctxp = (float*)(ws + OFF_CTXP) + g*(4*8*512);
  float*  lbp  = (float*)(ws + OFF_LB)   + g*32;
  unsigned* slots = (unsigned*)(ws + OFF_BAR) + g*32;
  const half_t* Penc = (const half_t*)(ws + OFF_PENC);
  const half_t* ench = (const half_t*)(ws + OFF_ENC);
  const half_t* gix  = (const half_t*)(ws + OFF_GIX);
  half_t* h2a = (half_t*)(ws + OFF_H2A);
  const half_t* w1 = (const half_t*)(ws + OFF_W1);
  const half_t* w3 = (const half_t*)(ws + OFF_W3);

  // ---- LDS (~119.4 KB) --------------------------------------------------
  __shared__ __align__(16) half_t PT[50*512];      // Penc tile [s][512]   51200 B
  __shared__ __align__(16) half_t ETT[512*56];     // enc tile  [h][s+pad] 57344 B
  __shared__ __align__(16) half_t hs[4*HS_STR];    // h staging (padded)    4160 B
  __shared__ __align__(16) half_t ctxs[4*HS_STR];  // ctx staging (padded)  4160 B
  __shared__ __align__(16) float accb[8][4][16];   // ph split-K partials
  __shared__ __align__(16) float ghb[3][2][4][16]; // gh partials
  __shared__ __align__(16) float gib[3][2][4][16]; // gi_c partials
  __shared__ __align__(16) float es[64];
  __shared__ float Ls[4];

  const int b_l = m & 3, ch = m >> 2;
  const int bglob = b0 + b_l;

  // ---- pre-loop: stage this block's Penc / enc slices into LDS ----------
  for (int i = tid; i < 50*64; i += 512){
    int s = i >> 6, c = i & 63;
    ((uint4*)PT)[s*64 + c] =
      *(const uint4*)(Penc + ((size_t)((ch*50 + s)*32 + bglob))*512 + c*8);
  }
  {
    const half_t* eb = ench + ((size_t)(ch*50)*32 + bglob)*512;
    for (int s = 0; s < 50; ++s)
      ETT[tid*56 + s] = eb[(size_t)s*16384 + tid];   // transpose: [h][s]
  }

  // ---- register-resident MFMA A-fragments (weights) ---------------------
  half8v w1a[2];
  {
    const half_t* wr = w1 + (size_t)(m*16 + r16)*512;
    #pragma unroll
    for (int q = 0; q < 2; ++q)
      w1a[q] = *(const half8v*)(wr + (2*w+q)*32 + kg*8);
  }
  half8v wha[8], w3a[8];
  if (w < 6){
    const int gate = w >> 1, kh = w & 1;
    const half_t* wr1 = w1 + (size_t)(512 + gate*512 + m*16 + r16)*512;
    const half_t* wr3 = w3 + (size_t)(gate*512 + m*16 + r16)*512;
    #pragma unroll
    for (int i = 0; i < 8; ++i){
      wha[i] = *(const half8v*)(wr1 + (kh*8+i)*32 + kg*8);
      w3a[i] = *(const half8v*)(wr3 + (kh*8+i)*32 + kg*8);
    }
  }
  float awr[8];
  #pragma unroll
  for (int i = 0; i < 8; ++i) awr[i] = attw[lane*8 + i];

  const int s0 = (w < 6) ? 6*w : 36 + 7*(w-6);   // 50 = 6*6 + 2*7
  const int ns = (w < 6) ? 6 : 7;
  float h2keep = 0.f;
  __syncthreads();   // LDS tiles ready

  for (int t = 0; t < Td; ++t){
    // ===== wait bar3 of previous step (trivial at t=0) ==================
    wait_slots(slots, 3u*t);
    // ===== phase 1: ph rows m*16..+16 via MFMA (split-K over 8 waves) ===
    {
      int bb = tid >> 7, h4 = (tid & 127) * 4;
      ((unsigned long long*)hs)[bb*130 + (h4 >> 2)] =
          ld_u64_l2(((const unsigned long long*)(hbuf + b0*512)) + tid);
    }
    __syncthreads();
    {
      f32x4 acc = {0.f, 0.f, 0.f, 0.f};
      #pragma unroll
      for (int q = 0; q < 2; ++q){
        half8v bf = *(const half8v*)(hs + (lane&3)*HS_STR + (2*w+q)*32 + kg*8);
        acc = __builtin_amdgcn_mfma_f32_16x16x32_f16(w1a[q], bf, acc, 0, 0, 0);
      }
      if (r16 < 4) *((f32x4*)&accb[w][lane&3][kg*4]) = acc;
    }
    __syncthreads();
    if (tid < 64){
      const int c = tid >> 4, r = tid & 15;
      float s = 0.f;
      #pragma unroll
      for (int w2 = 0; w2 < 8; ++w2) s += accb[w2][c][r];
      ph_g[c*512 + m*16 + r] = s;
    }
    // arrive1: wave 0 drains its own ph stores, then flags
    if (tid < 64){
      __asm__ __volatile__("s_waitcnt vmcnt(0)" ::: "memory");
      if (tid == 0) slot_store(slots, m, 3u*t + 1u);
    }
    // gh MFMA in the barrier shadow (LDS + registers only)
    if (w < 6){
      const int gate = w >> 1, kh = w & 1;
      f32x4 ga = {0.f, 0.f, 0.f, 0.f};
      #pragma unroll
      for (int i = 0; i < 8; ++i){
        half8v bf = *(const half8v*)(hs + (lane&3)*HS_STR + (kh*8+i)*32 + kg*8);
        ga = __builtin_amdgcn_mfma_f32_16x16x32_f16(wha[i], bf, ga, 0, 0, 0);
      }
      if (r16 < 4) *((f32x4*)&ghb[gate][kh][lane&3][kg*4]) = ga;
    }
    wait_slots(slots, 3u*t + 1u);
    // ===== phase 2: scores (LDS Penc) + softmax + ctx partial (LDS enc) ==
    {
      union { unsigned long long u[4]; float f[8]; } phu;
      const float* php = ph_g + b_l*512 + lane*8;
      #pragma unroll
      for (int q2 = 0; q2 < 4; ++q2)
        phu.u[q2] = ld_u64_l2(((const unsigned long long*)php) + q2);
      #pragma unroll
      for (int k = 0; k < 7; ++k){
        if (k >= ns) break;
        const int s_l = s0 + k;
        half8v pvv = *(const half8v*)(PT + s_l*512 + lane*8);
        float a = 0.f;
        #pragma unroll
        for (int i = 0; i < 8; ++i)
          a = fmaf(pade_tanh((float)pvv[i] + phu.f[i]), awr[i], a);
        #pragma unroll
        for (int o = 1; o < 64; o <<= 1) a += __shfl_xor(a, o);
        if (lane == 0) es[s_l] = a;
      }
      __syncthreads();
      if (tid < 64){
        float ev = 0.f;
        if (tid < 50){
          ev = __builtin_amdgcn_exp2f((es[tid] - 20.f) * 1.4426950408889634f);
          es[tid] = ev;    // fixed-offset softmax (|e| <= ||att_w||_1 ~ 18)
        }
        #pragma unroll
        for (int o = 1; o < 64; o <<= 1) ev += __shfl_xor(ev, o);
        if (tid == 0) lbp[b_l*8 + ch] = ev;    // plain store (no atomic)
      }
      __syncthreads();
      // ctx partial: 50-term dot per h=tid, all from LDS
      const half_t* rowp = ETT + tid*56;
      float acc2 = 0.f;
      #pragma unroll
      for (int q = 0; q < 6; ++q){
        half8v r8 = *(const half8v*)(rowp + q*8);
        f32x4 ea = *(const f32x4*)&es[q*8];
        f32x4 eb2 = *(const f32x4*)&es[q*8 + 4];
        acc2 = fmaf((float)r8[0], ea[0], acc2);
        acc2 = fmaf((float)r8[1], ea[1], acc2);
        acc2 = fmaf((float)r8[2], ea[2], acc2);
        acc2 = fmaf((float)r8[3], ea[3], acc2);
        acc2 = fmaf((float)r8[4], eb2[0], acc2);
        acc2 = fmaf((float)r8[5], eb2[1], acc2);
        acc2 = fmaf((float)r8[6], eb2[2], acc2);
        acc2 = fmaf((float)r8[7], eb2[3], acc2);
      }
      acc2 = fmaf((float)rowp[48], es[48], acc2);
      acc2 = fmaf((float)rowp[49], es[49], acc2);
      ctxp[(b_l*8 + ch)*512 + tid] = acc2;     // plain coalesced store
    }
    // arrive2: block-wide producers -> sync (drains vmcnt) then flag
    __syncthreads();
    if (tid == 0) slot_store(slots, m, 3u*t + 2u);
    // gix prefetch in the barrier shadow (HBM stream, ~900 cyc)
    float gxr = 0.f, gxz = 0.f, gxn = 0.f;
    if (tid < 64){
      const int bl = tid >> 4, jl = tid & 15;
      const int j = m*16 + jl, bg = b0 + bl;
      const half_t* gp = gix + ((size_t)t*32 + bg)*1536;
      gxr = (float)gp[j]; gxz = (float)gp[512 + j]; gxn = (float)gp[1024 + j];
    }
    wait_slots(slots, 3u*t + 2u);
    // ===== phase 3: combine ctx, gi_c MFMA, GRU update ==================
    if (tid < 32){
      float v = ld_f32_l2(&lbp[tid]);
      v += __shfl_xor(v, 1); v += __shfl_xor(v, 2); v += __shfl_xor(v, 4);
      if ((tid & 7) == 0) Ls[tid >> 3] = __builtin_amdgcn_rcpf(v);
    }
    float sums[4];
    #pragma unroll
    for (int rep = 0; rep < 4; ++rep){          // b = rep, h = tid
      float s = 0.f;
      #pragma unroll
      for (int c2 = 0; c2 < 8; ++c2)
        s += ld_f32_l2(&ctxp[(rep*8 + c2)*512 + tid]);
      sums[rep] = s;
    }
    __syncthreads();                            // Ls ready
    #pragma unroll
    for (int rep = 0; rep < 4; ++rep)
      ctxs[rep*HS_STR + tid] = (half_t)(sums[rep] * Ls[rep]);
    __syncthreads();
    if (w < 6){
      const int gate = w >> 1, kh = w & 1;
      f32x4 ia = {0.f, 0.f, 0.f, 0.f};
      #pragma unroll
      for (int i = 0; i < 8; ++i){
        half8v bf = *(const half8v*)(ctxs + (lane&3)*HS_STR + (kh*8+i)*32 + kg*8);
        ia = __builtin_amdgcn_mfma_f32_16x16x32_f16(w3a[i], bf, ia, 0, 0, 0);
      }
      if (r16 < 4) *((f32x4*)&gib[gate][kh][lane&3][kg*4]) = ia;
    }
    __syncthreads();
    if (tid < 64){
      const int bl = tid >> 4, jl = tid & 15;
      const int j = m*16 + jl, bg = b0 + bl;
      float xr = gxr + gib[0][0][bl][jl] + gib[0][1][bl][jl]
                     + ghb[0][0][bl][jl] + ghb[0][1][bl][jl];
      float xz = gxz + gib[1][0][bl][jl] + gib[1][1][bl][jl]
                     + ghb[1][0][bl][jl] + ghb[1][1][bl][jl];
      float xn = gxn + gib[2][0][bl][jl] + gib[2][1][bl][jl];
      float gnh = ghb[2][0][bl][jl] + ghb[2][1][bl][jl];
      float r = fast_sigmoid(xr);
      float z = fast_sigmoid(xz);
      float n = fast_tanh(xn + r * gnh);
      float h2v = (1.f - z) * n + z * h2keep;
      h2keep = h2v;
      hbuf[bg*512 + j] = (half_t)h2v;
      h2a[((size_t)t*32 + bg)*512 + j] = (half_t)h2v;
    }
    // arrive3: sync drains h2/h2a stores, then flag (wait at next-iter top)
    __syncthreads();
    if (tid == 0) slot_store(slots, m, 3u*t + 3u);
  }
}

// ---------------- launch --------------------------------------------------
extern "C" void kernel_launch(void* const* d_in, const int* in_sizes, int n_in,
                              void* d_out, int out_size, void* d_ws, size_t ws_size,
                              hipStream_t stream)
{
  const float* dec   = (const float*)d_in[0];
  const float* enc   = (const float*)d_in[1];
  const float* fcW   = (const float*)d_in[2];
  const float* attw  = (const float*)d_in[3];
  const float* Wih   = (const float*)d_in[4];
  const float* Whh   = (const float*)d_in[5];
  const float* specW = (const float*)d_in[6];
  const float* specb = (const float*)d_in[7];
  const float* gateW = (const float*)d_in[8];
  const float* gateb = (const float*)d_in[9];
  char* ws = (char*)d_ws;
  float* out = (float*)d_out;

  hipLaunchKernelGGL(k_init, dim3(33), dim3(256), 0, stream, ws);
  hipLaunchKernelGGL(k_prep_enc, dim3(2048), dim3(256), 0, stream,
                     enc, (half_t*)(ws + OFF_ENC), Sd*Bd*Hd);
  hipLaunchKernelGGL(k_prep_xs, dim3(2048), dim3(256), 0, stream,
                     dec, (half_t*)(ws + OFF_XS));
  hipLaunchKernelGGL(k_prep_w, dim3(1024), dim3(256), 0, stream,
                     fcW, Wih, Whh, specW, ws);
  // Penc = enc @ fc_W^T   (M=12800, N=512)
  hipLaunchKernelGGL((k_gemm<0>), dim3(8, 200), dim3(256), 0, stream,
                     (const half_t*)(ws + OFF_ENC), (const half_t*)(ws + OFF_W1),
                     (void*)(ws + OFF_PENC), 512, (const float*)nullptr);
  // GI_x = xs @ Wih_x^T   (M=12800, N=1536)
  hipLaunchKernelGGL((k_gemm<0>), dim3(24, 200), dim3(256), 0, stream,
                     (const half_t*)(ws + OFF_XS), (const half_t*)(ws + OFF_WX),
                     (void*)(ws + OFF_GIX), 1536, (const float*)nullptr);
  // recurrent loop
  hipLaunchKernelGGL(k_main, dim3(256), dim3(512), 0, stream, ws, attw);
  // mels = h2 @ spec_W^T + b, written (B,T,H)
  hipLaunchKernelGGL((k_gemm<1>), dim3(8, 200), dim3(256), 0, stream,
                     (const half_t*)(ws + OFF_H2A), (const half_t*)(ws + OFF_SPEC),
                     (void*)out, 512, specb);
  // gates = h2 @ gate_W + b, written (B,T)
  hipLaunchKernelGGL(k_gate, dim3(3200), dim3(256), 0, stream,
                     (const half_t*)(ws + OFF_H2A), gateW, gateb, out);
}